// Round 2
// baseline (18268.491 us; speedup 1.0000x reference)
//
#include <hip/hip_runtime.h>
#include <cstdint>
#include <cstddef>

// Problem dims
#define BDIM 32
#define TDIM 2048
#define IDIM 256
#define HDIM 256
#define CHUNK 256          // timesteps per gemm/lstm chunk
#define NCHUNK (TDIM / CHUNK)

using short8 = __attribute__((ext_vector_type(8))) short;
using f32x4  = __attribute__((ext_vector_type(4))) float;

__device__ __forceinline__ float bflo(uint32_t u) { return __uint_as_float(u << 16); }
__device__ __forceinline__ float bfhi(uint32_t u) { return __uint_as_float(u & 0xffff0000u); }
__device__ __forceinline__ uint16_t f2bf(float f) {
  uint32_t u = __float_as_uint(f);
  uint32_t r = u + 0x7fffu + ((u >> 16) & 1u);   // RNE
  return (uint16_t)(r >> 16);
}
__device__ __forceinline__ float sigmoidf_fast(float x) {
  return 1.f / (1.f + __expf(-x));
}
__device__ __forceinline__ float tanhf_fast(float x) {
  float a = fabsf(x);
  float e = __expf(2.f * a);        // overflow to inf is fine: t -> 1
  float t = 1.f - 2.f / (e + 1.f);
  return copysignf(t, x);
}

// ---------------- prep kernels ----------------

// fp32 -> bf16, 4 elems/thread
__global__ void k_cvt4(const float* __restrict__ src, uint16_t* __restrict__ dst, int n4) {
  int i = blockIdx.x * blockDim.x + threadIdx.x;
  if (i >= n4) return;
  const float4 v = ((const float4*)src)[i];
  ushort4 o;
  o.x = f2bf(v.x); o.y = f2bf(v.y); o.z = f2bf(v.z); o.w = f2bf(v.w);
  ((ushort4*)dst)[i] = o;
}

__global__ void k_zero(float* __restrict__ p, int n) {
  int i = blockIdx.x * blockDim.x + threadIdx.x;
  if (i < n) p[i] = 0.f;
}

// wcat[j][k], j in [0,2048): dir=j>>10, n=(j&1023)>>2, g=j&3 ; row of Wih_dir = g*256+n
__global__ void k_build_wcat(const float* __restrict__ wf, const float* __restrict__ wb,
                             const float* __restrict__ biasf, const float* __restrict__ biasb,
                             uint16_t* __restrict__ wcat, float* __restrict__ biasp) {
  int id = blockIdx.x * 256 + threadIdx.x;    // 0 .. 524287
  int k = id & 255;
  int j = id >> 8;
  int dir = j >> 10;
  int jj = j & 1023;
  int n = jj >> 2;
  int g = jj & 3;
  const float* W = dir ? wb : wf;
  wcat[id] = f2bf(W[(g * 256 + n) * 256 + k]);
  if (k == 0) biasp[j] = (dir ? biasb : biasf)[g * 256 + n];
}

// wrec[dir][k][n][g] = Whh_dir[g*256+n][k]
__global__ void k_build_wrec(const float* __restrict__ whf, const float* __restrict__ whb,
                             uint16_t* __restrict__ wrec) {
  int id = blockIdx.x * 256 + threadIdx.x;    // 0 .. 524287
  int g = id & 3;
  int n = (id >> 2) & 255;
  int k = (id >> 10) & 255;
  int dir = id >> 18;
  const float* W = dir ? whb : whf;
  wrec[id] = f2bf(W[(g * 256 + n) * 256 + k]);
}

// ---------------- input-projection GEMM (per chunk) ----------------
// Rows sm in [0, CHUNK*32): sm = s_local*32 + b. Cols j in [0,2048): dir*1024 + n*4 + g.
// A row = x[b, t(dir, c0+s_local)] (fp32, converted to bf16 in-register).
// C[sm][j] = sum_k A*Bw + bias. Tile 64x64, 4 waves.
__global__ __launch_bounds__(256) void k_gemm_xw(
    const float* __restrict__ x,       // [32][2048][256] fp32
    const uint16_t* __restrict__ Bw,   // wcat [2048][256] bf16
    const float* __restrict__ bias,    // [2048]
    uint16_t* __restrict__ C,          // xwc [CHUNK*32][2048] bf16
    int c0) {
  __shared__ float Cs[64 * 65];

  const int bid = blockIdx.x;
  const int mt = bid >> 5;     // CHUNK*32/64 tiles of 64 rows
  const int nt = bid & 31;     // 32 tiles of 64 cols
  const int dir = nt >> 4;
  const int tid = threadIdx.x;
  const int wid = tid >> 6;
  const int lane = tid & 63;
  const int l15 = lane & 15;
  const int lg  = lane >> 4;

  const int sm = mt * 64 + wid * 16 + l15;     // row this lane provides for A
  const int s_local = sm >> 5;
  const int b = sm & 31;
  const int t = dir ? (TDIM - 1 - (c0 + s_local)) : (c0 + s_local);

  const float*    Abase = x  + ((size_t)(b * TDIM + t)) * 256 + lg * 8;
  const uint16_t* Bbase = Bw + ((size_t)(nt * 64 + l15)) * 256 + lg * 8;

  f32x4 acc[4] = {};
#pragma unroll
  for (int ks = 0; ks < 8; ++ks) {
    const float4 f0 = *(const float4*)(Abase + ks * 32);
    const float4 f1 = *(const float4*)(Abase + ks * 32 + 4);
    short8 a;
    a[0] = (short)f2bf(f0.x); a[1] = (short)f2bf(f0.y);
    a[2] = (short)f2bf(f0.z); a[3] = (short)f2bf(f0.w);
    a[4] = (short)f2bf(f1.x); a[5] = (short)f2bf(f1.y);
    a[6] = (short)f2bf(f1.z); a[7] = (short)f2bf(f1.w);
#pragma unroll
    for (int ni = 0; ni < 4; ++ni) {
      const short8 bfr = *(const short8*)(Bbase + ni * 16 * 256 + ks * 32);
      acc[ni] = __builtin_amdgcn_mfma_f32_16x16x32_bf16(a, bfr, acc[ni], 0, 0, 0);
    }
  }

  // C/D layout: col=lane&15, row=(lane>>4)*4+reg  [m89]
#pragma unroll
  for (int ni = 0; ni < 4; ++ni) {
    const float bv = bias[nt * 64 + ni * 16 + l15];
    const int col = ni * 16 + l15;
#pragma unroll
    for (int r = 0; r < 4; ++r) {
      const int row = wid * 16 + lg * 4 + r;
      Cs[row * 65 + col] = acc[ni][r] + bv;
    }
  }
  __syncthreads();

  // Coalesced bf16 store
  const int row = tid >> 2;
  const int seg = tid & 3;
  uint16_t tmp[16] __attribute__((aligned(16)));
#pragma unroll
  for (int c = 0; c < 16; ++c) tmp[c] = f2bf(Cs[row * 65 + seg * 16 + c]);
  uint16_t* dst = C + ((size_t)(mt * 64 + row)) * 2048 + nt * 64 + seg * 16;
  *(short8*)(dst)     = *(const short8*)(tmp);
  *(short8*)(dst + 8) = *(const short8*)(tmp + 8);
}

// ---------------- recurrence (per chunk) ----------------
// 64 WGs: one per (batch, direction). 1024 threads: n = tid&255, q = tid>>8 (k-quarter).
__global__ __launch_bounds__(1024) void k_lstm(
    const uint16_t* __restrict__ xwc,  // [CHUNK*32][2048]: row sl*32+b, col dir*1024 + n*4 + g
    const uint16_t* __restrict__ wrec, // [2][256][256][4]
    uint16_t* __restrict__ hcat,       // [B][T][512]: dir*256 + n
    float* __restrict__ hstate,        // [64][256]
    float* __restrict__ cstate,        // [64][256]
    int c0) {
  __shared__ float hbuf[256];
  __shared__ float part[4][256][4];

  const int w = blockIdx.x;
  const int b = w >> 1;
  const int dir = w & 1;
  const int tid = threadIdx.x;
  const int n = tid & 255;
  const int q = tid >> 8;

  const uint16_t* wbase = wrec + dir * (256 * 256 * 4) + (q * 64) * (256 * 4) + n * 4;

  float c = 0.f;
  if (tid < 256) {
    hbuf[tid] = hstate[w * 256 + tid];
    c = cstate[w * 256 + tid];
  }
  __syncthreads();

  for (int sl = 0; sl < CHUNK; ++sl) {
    const int t = dir ? (TDIM - 1 - (c0 + sl)) : (c0 + sl);

    float ai = 0.f, af = 0.f, ag = 0.f, ao = 0.f;
    const uint16_t* wp = wbase;
#pragma unroll 8
    for (int kk = 0; kk < 64; ++kk) {
      const float hk = hbuf[q * 64 + kk];
      const uint2 wv = *(const uint2*)wp;
      wp += 1024;
      ai = fmaf(hk, bflo(wv.x), ai);
      af = fmaf(hk, bfhi(wv.x), af);
      ag = fmaf(hk, bflo(wv.y), ag);
      ao = fmaf(hk, bfhi(wv.y), ao);
    }
    f32x4 pv;
    pv[0] = ai; pv[1] = af; pv[2] = ag; pv[3] = ao;
    *(f32x4*)(&part[q][n][0]) = pv;
    __syncthreads();

    if (tid < 256) {
      const f32x4 p0 = *(const f32x4*)(&part[0][tid][0]);
      const f32x4 p1 = *(const f32x4*)(&part[1][tid][0]);
      const f32x4 p2 = *(const f32x4*)(&part[2][tid][0]);
      const f32x4 p3 = *(const f32x4*)(&part[3][tid][0]);
      float gi = p0[0] + p1[0] + p2[0] + p3[0];
      float gf = p0[1] + p1[1] + p2[1] + p3[1];
      float gg = p0[2] + p1[2] + p2[2] + p3[2];
      float go = p0[3] + p1[3] + p2[3] + p3[3];
      const uint2 xv = *(const uint2*)(xwc + ((size_t)(sl * 32 + b)) * 2048 + dir * 1024 + tid * 4);
      gi += bflo(xv.x); gf += bfhi(xv.x);
      gg += bflo(xv.y); go += bfhi(xv.y);
      const float I = sigmoidf_fast(gi);
      const float F = sigmoidf_fast(gf);
      const float G = tanhf_fast(gg);
      const float O = sigmoidf_fast(go);
      c = F * c + I * G;
      const float h = O * tanhf_fast(c);
      hbuf[tid] = h;
      hcat[((size_t)(b * TDIM + t)) * 512 + dir * 256 + tid] = f2bf(h);
    }
    __syncthreads();
  }

  if (tid < 256) {
    hstate[w * 256 + tid] = hbuf[tid];
    cstate[w * 256 + tid] = c;
  }
}

// ---------------- LayerNorm + FC ----------------
__global__ __launch_bounds__(256) void k_lnfc(
    const uint16_t* __restrict__ hcatp, // [BT][512]
    const float* __restrict__ lng, const float* __restrict__ lnb,
    const uint16_t* __restrict__ fcw,   // [256][512] bf16
    const float* __restrict__ fcb,
    float* __restrict__ out) {          // [BT][256]
  __shared__ float lnh[512];
  __shared__ float red[16];

  const int tid = threadIdx.x;
  const size_t bt = blockIdx.x;

  const uint32_t u = *(const uint32_t*)(hcatp + bt * 512 + tid * 2);
  const float v0 = bflo(u), v1 = bfhi(u);
  float s = v0 + v1;
  float s2 = v0 * v0 + v1 * v1;
#pragma unroll
  for (int o = 32; o; o >>= 1) {
    s  += __shfl_xor(s, o, 64);
    s2 += __shfl_xor(s2, o, 64);
  }
  const int wid = tid >> 6;
  if ((tid & 63) == 0) { red[wid] = s; red[wid + 4] = s2; }
  __syncthreads();
  if (tid == 0) {
    const float ts  = red[0] + red[1] + red[2] + red[3];
    const float ts2 = red[4] + red[5] + red[6] + red[7];
    const float mu  = ts * (1.f / 512.f);
    const float var = ts2 * (1.f / 512.f) - mu * mu;
    red[8] = mu;
    red[9] = rsqrtf(var + 1e-5f);
  }
  __syncthreads();
  const float mu = red[8], rs = red[9];
  lnh[tid * 2]     = (v0 - mu) * rs * lng[tid * 2]     + lnb[tid * 2];
  lnh[tid * 2 + 1] = (v1 - mu) * rs * lng[tid * 2 + 1] + lnb[tid * 2 + 1];
  __syncthreads();

  float acc = fcb[tid];
  const uint16_t* wr = fcw + (size_t)tid * 512;
#pragma unroll 4
  for (int k8 = 0; k8 < 64; ++k8) {
    const uint4 wv = *(const uint4*)(wr + k8 * 8);
    const float* l = &lnh[k8 * 8];
    acc = fmaf(bflo(wv.x), l[0], acc);
    acc = fmaf(bfhi(wv.x), l[1], acc);
    acc = fmaf(bflo(wv.y), l[2], acc);
    acc = fmaf(bfhi(wv.y), l[3], acc);
    acc = fmaf(bflo(wv.z), l[4], acc);
    acc = fmaf(bfhi(wv.z), l[5], acc);
    acc = fmaf(bflo(wv.w), l[6], acc);
    acc = fmaf(bfhi(wv.w), l[7], acc);
  }
  out[bt * 256 + tid] = acc;
}

// ---------------- launcher ----------------

extern "C" void kernel_launch(void* const* d_in, const int* in_sizes, int n_in,
                              void* d_out, int out_size, void* d_ws, size_t ws_size,
                              hipStream_t stream) {
  const float* x    = (const float*)d_in[0];
  const float* Wihf = (const float*)d_in[1];
  const float* Whhf = (const float*)d_in[2];
  const float* bf_  = (const float*)d_in[3];
  const float* Wihb = (const float*)d_in[4];
  const float* Whhb = (const float*)d_in[5];
  const float* bb_  = (const float*)d_in[6];
  const float* lng  = (const float*)d_in[7];
  const float* lnb  = (const float*)d_in[8];
  const float* fcW  = (const float*)d_in[9];
  const float* fcb  = (const float*)d_in[10];
  float* out = (float*)d_out;

  char* ws = (char*)d_ws;
  size_t off = 0;
  uint16_t* wcat  = (uint16_t*)(ws + off); off += (size_t)2048 * 256 * 2;         // 1.0 MB
  float*    biasp = (float*)(ws + off);    off += (size_t)2048 * 4;               // 8 KB
  uint16_t* wrec  = (uint16_t*)(ws + off); off += (size_t)2 * 256 * 256 * 4 * 2;  // 1.0 MB
  uint16_t* fcwb  = (uint16_t*)(ws + off); off += (size_t)256 * 512 * 2;          // 0.26 MB
  float*    hstate= (float*)(ws + off);    off += (size_t)64 * 256 * 4;           // 64 KB
  float*    cstate= (float*)(ws + off);    off += (size_t)64 * 256 * 4;           // 64 KB
  uint16_t* xwc   = (uint16_t*)(ws + off); off += (size_t)(CHUNK * 32) * 2048 * 2;// 33.5 MB
  uint16_t* hcat  = (uint16_t*)(ws + off); off += (size_t)65536 * 512 * 2;        // 67 MB
  (void)ws_size; (void)in_sizes; (void)n_in; (void)out_size;
  // total ~103 MB

  // prep: weight permutations + conversions + state zero
  k_cvt4<<<128, 256, 0, stream>>>(fcW, fcwb, 131072 / 4);
  k_build_wcat<<<2048, 256, 0, stream>>>(Wihf, Wihb, bf_, bb_, wcat, biasp);
  k_build_wrec<<<2048, 256, 0, stream>>>(Whhf, Whhb, wrec);
  k_zero<<<128, 256, 0, stream>>>(hstate, 64 * 256 * 2);   // hstate+cstate contiguous

  // chunked: input-projection GEMM then sequential recurrence
  for (int ck = 0; ck < NCHUNK; ++ck) {
    const int c0 = ck * CHUNK;
    k_gemm_xw<<<(CHUNK * 32 / 64) * 32, 256, 0, stream>>>(x, wcat, biasp, xwc, c0);
    k_lstm<<<64, 1024, 0, stream>>>(xwc, wrec, hcat, hstate, cstate, c0);
  }

  // LayerNorm + output projection
  k_lnfc<<<65536, 256, 0, stream>>>(hcat, lng, lnb, fcwb, fcb, out);
}

// Round 3
// 8639.767 us; speedup vs baseline: 2.1145x; 2.1145x over previous
//
#include <hip/hip_runtime.h>
#include <cstdint>
#include <cstddef>

// Problem dims
#define BDIM 32
#define TDIM 2048
#define IDIM 256
#define HDIM 256
#define CHUNK 128          // timesteps per fused chunk
#define NCHUNK (TDIM / CHUNK)
#define GEMM_WGS 512       // (CHUNK*32/128) * (2048/128) = 32*16

using short8 = __attribute__((ext_vector_type(8))) short;
using f32x4  = __attribute__((ext_vector_type(4))) float;
typedef _Float16 half2v __attribute__((ext_vector_type(2)));

__device__ __forceinline__ float bflo(uint32_t u) { return __uint_as_float(u << 16); }
__device__ __forceinline__ float bfhi(uint32_t u) { return __uint_as_float(u & 0xffff0000u); }
__device__ __forceinline__ uint16_t f2bf(float f) {
  uint32_t u = __float_as_uint(f);
  uint32_t r = u + 0x7fffu + ((u >> 16) & 1u);   // RNE
  return (uint16_t)(r >> 16);
}
__device__ __forceinline__ uint16_t f2h_bits(float f) {
  _Float16 h = (_Float16)f;
  return __builtin_bit_cast(uint16_t, h);
}
__device__ __forceinline__ float h2f(uint16_t b) {
  return (float)__builtin_bit_cast(_Float16, b);
}
__device__ __forceinline__ half2v as_h2(uint32_t u) {
  return __builtin_bit_cast(half2v, u);
}
__device__ __forceinline__ float h2lo(uint32_t u) { return (float)as_h2(u)[0]; }
__device__ __forceinline__ float h2hi(uint32_t u) { return (float)as_h2(u)[1]; }

#if __has_builtin(__builtin_amdgcn_fdot2)
__device__ __forceinline__ float DOT2(half2v a, half2v b, float c) {
  return __builtin_amdgcn_fdot2(a, b, c, false);
}
#else
__device__ __forceinline__ float DOT2(half2v a, half2v b, float c) {
  return c + (float)a[0] * (float)b[0] + (float)a[1] * (float)b[1];
}
#endif

__device__ __forceinline__ float sigmoidf_fast(float x) {
  return 1.f / (1.f + __expf(-x));
}
__device__ __forceinline__ float tanhf_fast(float x) {
  float a = fabsf(x);
  float e = __expf(2.f * a);
  float t = 1.f - 2.f / (e + 1.f);
  return copysignf(t, x);
}

// ---------------- prep kernels ----------------

__global__ void k_cvt4(const float* __restrict__ src, uint16_t* __restrict__ dst, int n4) {
  int i = blockIdx.x * blockDim.x + threadIdx.x;
  if (i >= n4) return;
  const float4 v = ((const float4*)src)[i];
  ushort4 o;
  o.x = f2bf(v.x); o.y = f2bf(v.y); o.z = f2bf(v.z); o.w = f2bf(v.w);
  ((ushort4*)dst)[i] = o;
}

__global__ void k_zero(float* __restrict__ p, int n) {
  int i = blockIdx.x * blockDim.x + threadIdx.x;
  if (i < n) p[i] = 0.f;
}

// wcat[j][k] (bf16), j: dir=j>>10, n=(j&1023)>>2, g=j&3 -> Wih_dir row g*256+n
__global__ void k_build_wcat(const float* __restrict__ wf, const float* __restrict__ wb,
                             const float* __restrict__ biasf, const float* __restrict__ biasb,
                             uint16_t* __restrict__ wcat, float* __restrict__ biasp) {
  int id = blockIdx.x * 256 + threadIdx.x;    // 0 .. 524287
  int k = id & 255;
  int j = id >> 8;
  int dir = j >> 10;
  int jj = j & 1023;
  int n = jj >> 2;
  int g = jj & 3;
  const float* W = dir ? wb : wf;
  wcat[id] = f2bf(W[(g * 256 + n) * 256 + k]);
  if (k == 0) biasp[j] = (dir ? biasb : biasf)[g * 256 + n];
}

// wrec2 (f16): [dir][kp(128)][n(256)][g*2+j] = Whh_dir[g*256+n][2kp+j]
__global__ void k_build_wrec2(const float* __restrict__ whf, const float* __restrict__ whb,
                              uint16_t* __restrict__ wrec2) {
  int id = blockIdx.x * 256 + threadIdx.x;    // 0 .. 524287
  int j  = id & 1;
  int g  = (id >> 1) & 3;
  int n  = (id >> 3) & 255;
  int kp = (id >> 11) & 127;
  int dir = (id >> 18) & 1;
  const float* W = dir ? whb : whf;
  wrec2[id] = f2h_bits(W[(g * 256 + n) * 256 + 2 * kp + j]);
}

// ---------------- fused LSTM-chunk + next-chunk GEMM ----------------
// blocks 0..63: LSTM for chunk at c0 (consumes xw_cons). blocks 64..: GEMM producing
// chunk at c0g into xw_prod. No intra-kernel dependency (double-buffered xw).
__global__ __launch_bounds__(1024) void k_fused(
    const float* __restrict__ x,        // [32][2048][256] fp32
    const uint16_t* __restrict__ wcat,  // [2048][256] bf16
    const float* __restrict__ biasp,    // [2048]
    uint16_t* __restrict__ xw_prod,     // [CHUNK*32][2048] f16
    const uint16_t* __restrict__ xw_cons,
    const uint16_t* __restrict__ wrec2, // [2][128][256][8] f16
    uint16_t* __restrict__ hcat,        // [B][T][512] f16
    float* __restrict__ hstate,         // [64][256]
    float* __restrict__ cstate,         // [64][256]
    int c0, int c0g, int do_lstm, int do_gemm) {
  const int tid = threadIdx.x;

  if (blockIdx.x < 64) {
    // ---------------- LSTM body ----------------
    if (!do_lstm) return;
    __shared__ uint16_t hhalf[256];          // h as f16
    __shared__ float part[4][256][4];

    const int w = blockIdx.x;
    const int b = w >> 1;
    const int dir = w & 1;
    const int n = tid & 255;
    const int q = tid >> 8;

    const uint16_t* wbase = wrec2 + ((size_t)(dir * 128 + q * 32) * 256 + n) * 8;

    float c = 0.f, hlast = 0.f;
    if (tid < 256) {
      hlast = hstate[w * 256 + tid];
      c = cstate[w * 256 + tid];
      hhalf[tid] = f2h_bits(hlast);
    }
    __syncthreads();

    for (int sl = 0; sl < CHUNK; ++sl) {
      const int t = dir ? (TDIM - 1 - (c0 + sl)) : (c0 + sl);

      // prefetch this step's xW row (f16 pairs) early
      uint2 xv;
      if (tid < 256)
        xv = *(const uint2*)(xw_cons + ((size_t)(sl * 32 + b)) * 2048 + dir * 1024 + tid * 4);

      float ai = 0.f, af = 0.f, ag = 0.f, ao = 0.f;
      const uint16_t* wp = wbase;
#pragma unroll 8
      for (int it = 0; it < 32; ++it) {
        const half2v hp = as_h2(*(const uint32_t*)&hhalf[2 * (q * 32 + it)]);  // uniform
        const uint4 wv = *(const uint4*)wp;
        wp += 2048;
        ai = DOT2(as_h2(wv.x), hp, ai);
        af = DOT2(as_h2(wv.y), hp, af);
        ag = DOT2(as_h2(wv.z), hp, ag);
        ao = DOT2(as_h2(wv.w), hp, ao);
      }
      f32x4 pv; pv[0] = ai; pv[1] = af; pv[2] = ag; pv[3] = ao;
      *(f32x4*)(&part[q][n][0]) = pv;
      __syncthreads();

      if (tid < 256) {
        const f32x4 p0 = *(const f32x4*)(&part[0][tid][0]);
        const f32x4 p1 = *(const f32x4*)(&part[1][tid][0]);
        const f32x4 p2 = *(const f32x4*)(&part[2][tid][0]);
        const f32x4 p3 = *(const f32x4*)(&part[3][tid][0]);
        float gi = p0[0] + p1[0] + p2[0] + p3[0] + h2lo(xv.x);
        float gf = p0[1] + p1[1] + p2[1] + p3[1] + h2hi(xv.x);
        float gg = p0[2] + p1[2] + p2[2] + p3[2] + h2lo(xv.y);
        float go = p0[3] + p1[3] + p2[3] + p3[3] + h2hi(xv.y);
        const float I = sigmoidf_fast(gi);
        const float F = sigmoidf_fast(gf);
        const float G = tanhf_fast(gg);
        const float O = sigmoidf_fast(go);
        c = F * c + I * G;
        const float h = O * tanhf_fast(c);
        hlast = h;
        const uint16_t hb = f2h_bits(h);
        hhalf[tid] = hb;
        hcat[((size_t)(b * TDIM + t)) * 512 + dir * 256 + tid] = hb;
      }
      __syncthreads();
    }

    if (tid < 256) {
      hstate[w * 256 + tid] = hlast;
      cstate[w * 256 + tid] = c;
    }
    return;
  }

  // ---------------- GEMM body (produce chunk c0g) ----------------
  if (!do_gemm) return;
  const int gb = blockIdx.x - 64;            // 0..511
  const int mt = gb >> 4;                    // 32 m-tiles of 128 rows
  const int nt = gb & 15;                    // 16 n-tiles of 128 cols
  const int dir = nt >> 3;
  const int wv_ = tid >> 6;
  const int wm = wv_ & 3;
  const int wn = wv_ >> 2;
  const int lane = tid & 63;
  const int l15 = lane & 15;
  const int lg  = lane >> 4;

  const float* Abase[2];
  int colg[2];
  const uint16_t* Bbase[2];
  float bv[2], fvv[2];
#pragma unroll
  for (int mi = 0; mi < 2; ++mi) {
    const int row = mt * 128 + wm * 32 + mi * 16 + l15;
    const int s_local = row >> 5;
    const int b = row & 31;
    const int t = dir ? (TDIM - 1 - (c0g + s_local)) : (c0g + s_local);
    Abase[mi] = x + ((size_t)(b * TDIM + t)) * 256 + lg * 8;
  }
#pragma unroll
  for (int ni = 0; ni < 2; ++ni) {
    colg[ni] = nt * 128 + wn * 32 + ni * 16 + l15;
    Bbase[ni] = wcat + (size_t)colg[ni] * 256 + lg * 8;
    bv[ni] = biasp[colg[ni]];
    (void)fvv;
  }

  f32x4 acc[2][2] = {};
#pragma unroll
  for (int ks = 0; ks < 8; ++ks) {
    short8 a[2];
#pragma unroll
    for (int mi = 0; mi < 2; ++mi) {
      const float4 f0 = *(const float4*)(Abase[mi] + ks * 32);
      const float4 f1 = *(const float4*)(Abase[mi] + ks * 32 + 4);
      a[mi][0] = (short)f2bf(f0.x); a[mi][1] = (short)f2bf(f0.y);
      a[mi][2] = (short)f2bf(f0.z); a[mi][3] = (short)f2bf(f0.w);
      a[mi][4] = (short)f2bf(f1.x); a[mi][5] = (short)f2bf(f1.y);
      a[mi][6] = (short)f2bf(f1.z); a[mi][7] = (short)f2bf(f1.w);
    }
#pragma unroll
    for (int ni = 0; ni < 2; ++ni) {
      const short8 bfr = *(const short8*)(Bbase[ni] + ks * 32);
#pragma unroll
      for (int mi = 0; mi < 2; ++mi)
        acc[mi][ni] = __builtin_amdgcn_mfma_f32_16x16x32_bf16(a[mi], bfr, acc[mi][ni], 0, 0, 0);
    }
  }

  // direct f16 store; C/D layout col=l15, row=lg*4+r
#pragma unroll
  for (int mi = 0; mi < 2; ++mi)
#pragma unroll
    for (int ni = 0; ni < 2; ++ni)
#pragma unroll
      for (int r = 0; r < 4; ++r) {
        const int row = mt * 128 + wm * 32 + mi * 16 + lg * 4 + r;
        xw_prod[(size_t)row * 2048 + colg[ni]] = f2h_bits(acc[mi][ni][r] + bv[ni]);
      }
}

// ---------------- LayerNorm + FC (MFMA) ----------------
// 1024 WGs x 256 thr; WG handles 64 bt-rows. hcat f16 [BT][512] -> out f32 [BT][256].
__global__ __launch_bounds__(256) void k_lnfc2(
    const uint16_t* __restrict__ hcat,
    const float* __restrict__ lng, const float* __restrict__ lnb,
    const uint16_t* __restrict__ fcwb,  // [256][512] bf16
    const float* __restrict__ fcb,
    float* __restrict__ out) {
  __shared__ uint16_t lnh[64 * 520];   // normalized bf16, row pad 8
  __shared__ float slng[512], slnb[512];

  const int tid = threadIdx.x;
  const size_t bt0 = (size_t)blockIdx.x * 64;

  slng[tid] = lng[tid]; slng[tid + 256] = lng[tid + 256];
  slnb[tid] = lnb[tid]; slnb[tid + 256] = lnb[tid + 256];

  // stats: 4 threads per row, each 128 elems
  const int row = tid >> 2;
  const int part = tid & 3;
  const uint16_t* hrow = hcat + (bt0 + row) * 512;
  float s = 0.f, s2 = 0.f;
#pragma unroll
  for (int i = 0; i < 16; ++i) {
    const uint4 u = *(const uint4*)(hrow + (i * 4 + part) * 8);
    const float f0 = h2lo(u.x), f1 = h2hi(u.x), f2 = h2lo(u.y), f3 = h2hi(u.y);
    const float f4 = h2lo(u.z), f5 = h2hi(u.z), f6 = h2lo(u.w), f7 = h2hi(u.w);
    s  += ((f0 + f1) + (f2 + f3)) + ((f4 + f5) + (f6 + f7));
    s2 += ((f0*f0 + f1*f1) + (f2*f2 + f3*f3)) + ((f4*f4 + f5*f5) + (f6*f6 + f7*f7));
  }
  s  += __shfl_xor(s, 1, 64);  s  += __shfl_xor(s, 2, 64);
  s2 += __shfl_xor(s2, 1, 64); s2 += __shfl_xor(s2, 2, 64);
  const float mu = s * (1.f / 512.f);
  const float var = s2 * (1.f / 512.f) - mu * mu;
  const float rs = rsqrtf(var + 1e-5f);
  __syncthreads();   // slng/slnb ready

  // normalize -> LDS bf16
#pragma unroll
  for (int i = 0; i < 16; ++i) {
    const int kb = (i * 4 + part) * 8;
    const uint4 u = *(const uint4*)(hrow + kb);
    uint16_t tmp[8] __attribute__((aligned(16)));
    const float f[8] = { h2lo(u.x), h2hi(u.x), h2lo(u.y), h2hi(u.y),
                         h2lo(u.z), h2hi(u.z), h2lo(u.w), h2hi(u.w) };
#pragma unroll
    for (int e = 0; e < 8; ++e)
      tmp[e] = f2bf((f[e] - mu) * rs * slng[kb + e] + slnb[kb + e]);
    *(short8*)&lnh[row * 520 + kb] = *(const short8*)tmp;
  }
  __syncthreads();

  // MFMA: wave w -> cols w*64..+64, all 64 rows, K=512
  const int w = tid >> 6;
  const int lane = tid & 63;
  const int l15 = lane & 15;
  const int lg = lane >> 4;
  f32x4 acc[4][4] = {};
#pragma unroll
  for (int nf = 0; nf < 4; ++nf) {
    const uint16_t* bb = fcwb + (size_t)(w * 64 + nf * 16 + l15) * 512 + lg * 8;
#pragma unroll 4
    for (int k0 = 0; k0 < 16; ++k0) {
      const short8 bfr = *(const short8*)(bb + k0 * 32);
#pragma unroll
      for (int mf = 0; mf < 4; ++mf) {
        const short8 afr = *(const short8*)&lnh[(mf * 16 + l15) * 520 + k0 * 32 + lg * 8];
        acc[mf][nf] = __builtin_amdgcn_mfma_f32_16x16x32_bf16(afr, bfr, acc[mf][nf], 0, 0, 0);
      }
    }
  }
#pragma unroll
  for (int nf = 0; nf < 4; ++nf) {
    const int col = w * 64 + nf * 16 + l15;
    const float fv = fcb[col];
#pragma unroll
    for (int mf = 0; mf < 4; ++mf)
#pragma unroll
      for (int r = 0; r < 4; ++r)
        out[(bt0 + mf * 16 + lg * 4 + r) * 256 + col] = acc[mf][nf][r] + fv;
  }
}

// ---------------- launcher ----------------

extern "C" void kernel_launch(void* const* d_in, const int* in_sizes, int n_in,
                              void* d_out, int out_size, void* d_ws, size_t ws_size,
                              hipStream_t stream) {
  const float* x    = (const float*)d_in[0];
  const float* Wihf = (const float*)d_in[1];
  const float* Whhf = (const float*)d_in[2];
  const float* bf_  = (const float*)d_in[3];
  const float* Wihb = (const float*)d_in[4];
  const float* Whhb = (const float*)d_in[5];
  const float* bb_  = (const float*)d_in[6];
  const float* lng  = (const float*)d_in[7];
  const float* lnb  = (const float*)d_in[8];
  const float* fcW  = (const float*)d_in[9];
  const float* fcb  = (const float*)d_in[10];
  float* out = (float*)d_out;

  char* ws = (char*)d_ws;
  size_t off = 0;
  uint16_t* wcat  = (uint16_t*)(ws + off); off += (size_t)2048 * 256 * 2;          // 1.0 MB
  float*    biasp = (float*)(ws + off);    off += (size_t)2048 * 4;                // 8 KB
  uint16_t* wrec2 = (uint16_t*)(ws + off); off += (size_t)2 * 128 * 256 * 8 * 2;   // 1.0 MB
  uint16_t* fcwb  = (uint16_t*)(ws + off); off += (size_t)256 * 512 * 2;           // 0.26 MB
  float*    hstate= (float*)(ws + off);    off += (size_t)64 * 256 * 4;            // 64 KB
  float*    cstate= (float*)(ws + off);    off += (size_t)64 * 256 * 4;            // 64 KB
  uint16_t* xw0   = (uint16_t*)(ws + off); off += (size_t)(CHUNK * 32) * 2048 * 2; // 16.8 MB
  uint16_t* xw1   = (uint16_t*)(ws + off); off += (size_t)(CHUNK * 32) * 2048 * 2; // 16.8 MB
  uint16_t* hcat  = (uint16_t*)(ws + off); off += (size_t)65536 * 512 * 2;         // 67 MB
  (void)ws_size; (void)in_sizes; (void)n_in; (void)out_size;
  // total ~103 MB

  k_cvt4<<<128, 256, 0, stream>>>(fcW, fcwb, 131072 / 4);
  k_build_wcat<<<2048, 256, 0, stream>>>(Wihf, Wihb, bf_, bb_, wcat, biasp);
  k_build_wrec2<<<2048, 256, 0, stream>>>(Whhf, Whhb, wrec2);
  k_zero<<<128, 256, 0, stream>>>(hstate, 64 * 256 * 2);   // hstate+cstate contiguous

  // prologue: produce chunk 0 into xw0 (lstm part inactive)
  k_fused<<<64 + GEMM_WGS, 1024, 0, stream>>>(x, wcat, biasp, xw0, xw1, wrec2,
                                              hcat, hstate, cstate, 0, 0, 0, 1);

  for (int ck = 0; ck < NCHUNK; ++ck) {
    uint16_t* cons = (ck & 1) ? xw1 : xw0;
    uint16_t* prod = (ck & 1) ? xw0 : xw1;
    const int dg = (ck < NCHUNK - 1) ? 1 : 0;
    const int grid = 64 + (dg ? GEMM_WGS : 0);
    k_fused<<<grid, 1024, 0, stream>>>(x, wcat, biasp, prod, cons, wrec2,
                                       hcat, hstate, cstate,
                                       ck * CHUNK, (ck + 1) * CHUNK, 1, dg);
  }

  k_lnfc2<<<1024, 256, 0, stream>>>(hcat, lng, lnb, fcwb, fcb, out);
}